// Round 1
// 1058.680 us; speedup vs baseline: 1.4012x; 1.4012x over previous
//
#include <hip/hip_runtime.h>
#include <stdint.h>

#define NBATCH 512
#define NT     2048
#define NK     8
#define ND     32
#define PF     4   // prefetch ring depth == inner unroll

// One wave (64 lanes) per batch element b. lane = (i = lane&31, kh = lane>>5).
// Each lane holds A[kh*4+kk][i][0..31] in 128 f32 VGPRs. z broadcast via
// v_readlane into SGPRs each step: no LDS, no barriers.
//
// R1 changes vs 1477us baseline:
//  - dot chains split 32-deep -> 2x16-deep (dep-FMA latency off critical path)
//  - per-lane loads ONLY its kh-half weight float4 (kills 4 cndmask selects,
//    halves weight ring VGPRs); wsum = half-sum + shfl_xor(32), off-path
//  - b_s folded into chain init; epilogue fused to 2 FMA
//  - prefetch ring deepened 2 -> 4 steps (~4x HBM miss latency of slack)
__global__ __launch_bounds__(64, 1) void slds_kernel(
    const float* __restrict__ z0,
    const float* __restrict__ s_probs,
    const float* __restrict__ noise,
    const float* __restrict__ A_s,
    const float* __restrict__ b_s,
    const float* __restrict__ Q_chol,
    float* __restrict__ ys)
{
    const int b    = blockIdx.x;
    const int lane = threadIdx.x;
    const int i    = lane & 31;
    const int kh   = lane >> 5;

    const float dt  = 0.05f;
    const float sdt = 0.22360679774997896f; // sqrt(0.05)

    // ---- A slice into registers (f32), 16B vector loads ----
    float a[4][ND];
#pragma unroll
    for (int kk = 0; kk < 4; ++kk) {
        const float4* ap = (const float4*)(A_s + (((size_t)(kh * 4 + kk) * ND + i) * ND));
#pragma unroll
        for (int q = 0; q < 8; ++q) {
            float4 v = ap[q];
            a[kk][q * 4 + 0] = v.x;
            a[kk][q * 4 + 1] = v.y;
            a[kk][q * 4 + 2] = v.z;
            a[kk][q * 4 + 3] = v.w;
        }
    }
    float breg[4], qreg[4];
#pragma unroll
    for (int kk = 0; kk < 4; ++kk) {
        breg[kk] = b_s[(kh * 4 + kk) * ND + i];
        qreg[kk] = Q_chol[(kh * 4 + kk) * ND + i];
    }

    // ---- z: own element + SGPR broadcast via readlane ----
    float zi = z0[b * ND + i];
    float z[ND];
#pragma unroll
    for (int j = 0; j < ND; ++j)
        z[j] = __int_as_float(__builtin_amdgcn_readlane(__float_as_int(zi), j));

    const float4* wbase = (const float4*)s_probs;  // [T][B][2] float4
    const float*  nbase = noise;

    // ---- 4-deep software pipeline: each lane loads only ITS kh-half float4 ----
    float4 wv[PF];
    float  nr[PF];
#pragma unroll
    for (int u = 0; u < PF; ++u) {
        const size_t o = (size_t)u * (NBATCH * 2) + (size_t)b * 2 + kh;
        wv[u] = wbase[o];
        nr[u] = nbase[((size_t)u * NBATCH + b) * ND + i];
    }

    for (int t = 0; t < NT; t += PF) {
#pragma unroll
        for (int u = 0; u < PF; ++u) {
            const int tt = t + u;
            const float4 wa  = wv[u];
            const float  nrc = nr[u];

            // prefetch step tt+PF into this slot (clamped; redundant tail load ok)
            int tp = tt + PF; if (tp > NT - 1) tp = NT - 1;
            const size_t op = (size_t)tp * (NBATCH * 2) + (size_t)b * 2 + kh;
            wv[u] = wbase[op];
            nr[u] = nbase[((size_t)tp * NBATCH + b) * ND + i];

            // my half's 4 weights; wsum via one cross-half shfl (same rounding
            // tree as before: (w0+w1)+(w2+w3) then + other half's sum)
            const float w0 = wa.x, w1 = wa.y, w2 = wa.z, w3 = wa.w;
            float psum = (w0 + w1) + (w2 + w3);
            float wsum = psum + __shfl_xor(psum, 32);
            float inv  = __builtin_amdgcn_rcpf(wsum);
            float g    = sdt * nrc;           // off critical path

            // y_k[i] = b_k[i] + sum_j A[k][i][j] z[j], two 16-deep chains each
            float acc = 0.f, qacc = 0.f;
            {
                const float wk0 = w0, wk1 = w1, wk2 = w2, wk3 = w3;
#pragma unroll
                for (int kk = 0; kk < 4; ++kk) {
                    float y0 = breg[kk];
                    float y1 = 0.f;
#pragma unroll
                    for (int j = 0; j < 16; ++j) {
                        y0 = fmaf(a[kk][j],      z[j],      y0);
                        y1 = fmaf(a[kk][j + 16], z[j + 16], y1);
                    }
                    const float wk = (kk == 0) ? wk0 : (kk == 1) ? wk1 : (kk == 2) ? wk2 : wk3;
                    acc  = fmaf(wk, y0 + y1, acc);
                    qacc = fmaf(wk, qreg[kk], qacc);
                }
            }

            // combine the two k-halves (single cross-lane op each)
            acc  += __shfl_xor(acc, 32);
            qacc += __shfl_xor(qacc, 32);

            // znew = zi + inv*(dt*acc + g*qacc)  (2 FMA + 1 mul epilogue)
            float znew = fmaf(inv, fmaf(dt, acc, g * qacc), zi);

            const size_t oofs = ((size_t)tt * NBATCH + b) * ND + i;
            if (lane < 32) {
                __builtin_nontemporal_store(znew, &ys[oofs]);  // streamed, never re-read
            }

            // broadcast znew to all lanes' z[] via readlane (VALU only)
#pragma unroll
            for (int j = 0; j < ND; ++j)
                z[j] = __int_as_float(__builtin_amdgcn_readlane(__float_as_int(znew), j));
            zi = znew;
        }
    }
}

extern "C" void kernel_launch(void* const* d_in, const int* in_sizes, int n_in,
                              void* d_out, int out_size, void* d_ws, size_t ws_size,
                              hipStream_t stream) {
    const float* z0 = (const float*)d_in[0];
    const float* sp = (const float*)d_in[1];
    const float* no = (const float*)d_in[2];
    const float* As = (const float*)d_in[3];
    const float* bs = (const float*)d_in[4];
    const float* Qc = (const float*)d_in[5];
    float* ys = (float*)d_out;

    slds_kernel<<<dim3(NBATCH), dim3(64), 0, stream>>>(z0, sp, no, As, bs, Qc, ys);
}

// Round 3
// 961.053 us; speedup vs baseline: 1.5436x; 1.1016x over previous
//
#include <hip/hip_runtime.h>
#include <stdint.h>

#define NBATCH 512
#define NT     2048
#define NK     8
#define ND     32
#define PF     4   // prefetch ring depth == inner unroll

typedef float f2 __attribute__((ext_vector_type(2)));
typedef unsigned int u2 __attribute__((ext_vector_type(2)));

// Cross-half (lane ^ 32) sum. v_permlane32_swap_b32 with dst=src=x returns
// {row0 broadcast to both rows, row1 broadcast to both rows}, so r0+r1 is
// the full cross-half sum in every lane. Pure VALU (~8cyc) vs the
// ds_permute path __shfl_xor(x,32) (~40cyc LDS-pipe latency).
__device__ __forceinline__ float halfsum(float x) {
#if defined(__has_builtin) && __has_builtin(__builtin_amdgcn_permlane32_swap)
    u2 r = __builtin_amdgcn_permlane32_swap(__float_as_uint(x), __float_as_uint(x),
                                            false, false);
    return __uint_as_float(r.x) + __uint_as_float(r.y);
#else
    return x + __shfl_xor(x, 32);
#endif
}

// One wave (64 lanes) per batch element b. lane = (i = lane&31, kh = lane>>5).
// Each lane holds A[kh*4+kk][i][0..31] in 64 f2 VGPR-pairs. z broadcast via
// v_readlane each step: no LDS, no barriers.
//
// R2 changes vs 920us R1:
//  - dot products on float2 via __builtin_elementwise_fma -> v_pk_fma_f32
//    (full-rate packed fp32 on CDNA4): 128 fma -> 64 pk_fma issue slots
//  - __shfl_xor(x,32) -> permlane32_swap builtin (VALU) for all 3 reductions
__global__ __launch_bounds__(64, 1) void slds_kernel(
    const float* __restrict__ z0,
    const float* __restrict__ s_probs,
    const float* __restrict__ noise,
    const float* __restrict__ A_s,
    const float* __restrict__ b_s,
    const float* __restrict__ Q_chol,
    float* __restrict__ ys)
{
    const int b    = blockIdx.x;
    const int lane = threadIdx.x;
    const int i    = lane & 31;
    const int kh   = lane >> 5;

    const float dt  = 0.05f;
    const float sdt = 0.22360679774997896f; // sqrt(0.05)

    // ---- A slice into registers as f2 pairs, 16B vector loads ----
    f2 a2[4][16];
#pragma unroll
    for (int kk = 0; kk < 4; ++kk) {
        const float4* ap = (const float4*)(A_s + (((size_t)(kh * 4 + kk) * ND + i) * ND));
#pragma unroll
        for (int q = 0; q < 8; ++q) {
            float4 v = ap[q];
            a2[kk][q * 2 + 0] = f2{v.x, v.y};
            a2[kk][q * 2 + 1] = f2{v.z, v.w};
        }
    }
    float breg[4], qreg[4];
#pragma unroll
    for (int kk = 0; kk < 4; ++kk) {
        breg[kk] = b_s[(kh * 4 + kk) * ND + i];
        qreg[kk] = Q_chol[(kh * 4 + kk) * ND + i];
    }

    // ---- z: own element + broadcast via readlane ----
    float zi = z0[b * ND + i];
    f2 z2[16];
#pragma unroll
    for (int j = 0; j < 16; ++j) {
        z2[j].x = __int_as_float(__builtin_amdgcn_readlane(__float_as_int(zi), 2 * j));
        z2[j].y = __int_as_float(__builtin_amdgcn_readlane(__float_as_int(zi), 2 * j + 1));
    }

    const float4* wbase = (const float4*)s_probs;  // [T][B][2] float4
    const float*  nbase = noise;

    // ---- 4-deep software pipeline: each lane loads only ITS kh-half float4 ----
    float4 wv[PF];
    float  nr[PF];
#pragma unroll
    for (int u = 0; u < PF; ++u) {
        const size_t o = (size_t)u * (NBATCH * 2) + (size_t)b * 2 + kh;
        wv[u] = wbase[o];
        nr[u] = nbase[((size_t)u * NBATCH + b) * ND + i];
    }

    for (int t = 0; t < NT; t += PF) {
#pragma unroll
        for (int u = 0; u < PF; ++u) {
            const int tt = t + u;
            const float4 wa  = wv[u];
            const float  nrc = nr[u];

            // prefetch step tt+PF into this slot (clamped; redundant tail load ok)
            int tp = tt + PF; if (tp > NT - 1) tp = NT - 1;
            const size_t op = (size_t)tp * (NBATCH * 2) + (size_t)b * 2 + kh;
            wv[u] = wbase[op];
            nr[u] = nbase[((size_t)tp * NBATCH + b) * ND + i];

            // my half's 4 weights; wsum via one cross-half swap (off dot path)
            const float w0 = wa.x, w1 = wa.y, w2 = wa.z, w3 = wa.w;
            float psum = (w0 + w1) + (w2 + w3);
            float wsum = halfsum(psum);
            float inv  = __builtin_amdgcn_rcpf(wsum);
            float g    = sdt * nrc;           // off critical path

            // y_k[i] = b_k[i] + sum_j A[k][i][j] z[j]; 16-deep packed chains
            float acc = 0.f, qacc = 0.f;
#pragma unroll
            for (int kk = 0; kk < 4; ++kk) {
                f2 y01 = f2{breg[kk], 0.f};
#pragma unroll
                for (int j = 0; j < 16; ++j)
                    y01 = __builtin_elementwise_fma(a2[kk][j], z2[j], y01);
                const float wk = (kk == 0) ? w0 : (kk == 1) ? w1 : (kk == 2) ? w2 : w3;
                acc  = fmaf(wk, y01.x + y01.y, acc);
                qacc = fmaf(wk, qreg[kk], qacc);
            }

            // combine the two k-halves (VALU swap, both independent)
            acc  = halfsum(acc);
            qacc = halfsum(qacc);

            // znew = zi + inv*(dt*acc + g*qacc)
            float znew = fmaf(inv, fmaf(dt, acc, g * qacc), zi);

            const size_t oofs = ((size_t)tt * NBATCH + b) * ND + i;
            if (lane < 32) {
                __builtin_nontemporal_store(znew, &ys[oofs]);  // streamed, never re-read
            }

            // broadcast znew to all lanes' z2[] via readlane
#pragma unroll
            for (int j = 0; j < 16; ++j) {
                z2[j].x = __int_as_float(__builtin_amdgcn_readlane(__float_as_int(znew), 2 * j));
                z2[j].y = __int_as_float(__builtin_amdgcn_readlane(__float_as_int(znew), 2 * j + 1));
            }
            zi = znew;
        }
    }
}

extern "C" void kernel_launch(void* const* d_in, const int* in_sizes, int n_in,
                              void* d_out, int out_size, void* d_ws, size_t ws_size,
                              hipStream_t stream) {
    const float* z0 = (const float*)d_in[0];
    const float* sp = (const float*)d_in[1];
    const float* no = (const float*)d_in[2];
    const float* As = (const float*)d_in[3];
    const float* bs = (const float*)d_in[4];
    const float* Qc = (const float*)d_in[5];
    float* ys = (float*)d_out;

    slds_kernel<<<dim3(NBATCH), dim3(64), 0, stream>>>(z0, sp, no, As, bs, Qc, ys);
}